// Round 12
// baseline (420.363 us; speedup 1.0000x reference)
//
#include <hip/hip_runtime.h>
#include <hip/hip_bf16.h>

typedef float f32x4 __attribute__((ext_vector_type(4)));
typedef __bf16 bf16x8 __attribute__((ext_vector_type(8)));
typedef unsigned short u16x4 __attribute__((ext_vector_type(4)));
typedef unsigned short u16x8 __attribute__((ext_vector_type(8)));

__device__ __forceinline__ unsigned short f2bf(float f) {
  union { float f; unsigned u; } x; x.f = f;
  unsigned r = x.u + 0x7FFFu + ((x.u >> 16) & 1u);
  return (unsigned short)(r >> 16);
}

__device__ __forceinline__ void gl16(const void* g, void* l) {
  __builtin_amdgcn_global_load_lds(
      (const __attribute__((address_space(1))) unsigned*)g,
      (__attribute__((address_space(3))) unsigned*)l, 16, 0, 0);
}

// ---------------- prep: W[k][n] f32 -> WT[n][k] bf16 (4 mats: q,k,v,o) ----
__global__ __launch_bounds__(256) void prep_wt(const float* __restrict__ Wq,
                                               const float* __restrict__ Wk,
                                               const float* __restrict__ Wv,
                                               const float* __restrict__ Wo,
                                               unsigned short* __restrict__ WT) {
  __shared__ unsigned short ts[64][65];
  const float* W = (blockIdx.z == 0) ? Wq : (blockIdx.z == 1) ? Wk
                   : (blockIdx.z == 2) ? Wv : Wo;
  const int t = threadIdx.x;
  const int kbase = blockIdx.y * 64;
  const int nbase = blockIdx.x * 64;
  for (int i = 0; i < 16; ++i) {
    int idx = i * 256 + t;
    int r = idx >> 6, c = idx & 63;
    ts[r][c] = f2bf(W[(size_t)(kbase + r) * 512 + nbase + c]);
  }
  __syncthreads();
  unsigned short* dst = WT + (size_t)blockIdx.z * 512 * 512;
  for (int i = 0; i < 16; ++i) {
    int idx = i * 256 + t;
    int nn = idx >> 6, kk = idx & 63;
    dst[(size_t)(nbase + nn) * 512 + kbase + kk] = ts[kk][nn];
  }
}

__global__ void prep_bias(const float* __restrict__ bq, const float* __restrict__ bk,
                          const float* __restrict__ bv, float* __restrict__ biasc) {
  int i = blockIdx.x * 256 + threadIdx.x;
  if (i < 512) biasc[i] = bq[i];
  else if (i < 1024) biasc[i] = bk[i - 512];
  else if (i < 1536) biasc[i] = bv[i - 1024];
}

// ---------------- QKV GEMM: C(bf16) = cvt_bf16(A_f32) @ BT^T + bias -------
// A f32 [M][512] read DIRECTLY (no convert pass): deep reg-staged pipeline
// LA (global f32x4, issued 4-6 phases early) -> WA (cvt + ds_write_b128
// into the SAME swizzled layout LDS[row][s]=G[row][s^(row&7)]). B via gl16
// (inverse-swizzled src). Counted vmcnt(12)+lgkm at p3/p7. Ledger in
// comments; every phase bracketed by memory-clobber asm (no load sinking).
__global__ __launch_bounds__(512, 2) void gemm256_f32a(
    const float* __restrict__ A, int lda,
    const unsigned short* __restrict__ BT,
    unsigned short* __restrict__ C, int ldc,
    const float* __restrict__ bias, int NB) {
  __shared__ alignas(16) unsigned short pool[66048];  // A0|A1|B0|B1 + epi pad
  const int t = threadIdx.x;
  const int lane = t & 63;
  const int w = t >> 6;
  const int wm = w >> 2, wn = w & 3;

  const int nwg = gridDim.x;
  const int cpx = nwg >> 3;
  const int wg = (blockIdx.x & 7) * cpx + (blockIdx.x >> 3);
  const int n0 = (wg % NB) * 256;
  const int m0 = (wg / NB) * 256;

  // B staging (gl16, inverse-swizzled src) -- verified path
  const int sr = lane >> 3;
  const int sg = ((lane & 7) ^ sr) << 3;
  const unsigned short* gB = BT + (size_t)(n0 + w * 8 + sr) * 512 + sg;
  const int lw = w * 512;
#define SBa(kt, b)                                                          \
  { const unsigned short* g_ = gB + (kt) * 64;                              \
    unsigned short* l_ = &pool[32768 + (b) * 16384 + lw];                   \
    gl16(g_, l_); gl16(g_ + (size_t)64 * 512, l_ + 4096); }
#define SBb(kt, b)                                                          \
  { const unsigned short* g_ = gB + (size_t)128 * 512 + (kt) * 64;          \
    unsigned short* l_ = &pool[32768 + (b) * 16384 + 8192 + lw];            \
    gl16(g_, l_); gl16(g_ + (size_t)64 * 512, l_ + 4096); }

  // A reg staging: thread t -> rows (t>>3)+u*64 (u=0..3), granule t&7.
  // Global col pre-swizzled so LDS stays linear-in-slot: same involution.
  const int arow = t >> 3;
  const int aseg = t & 7;
  const float* gA = A + (size_t)(m0 + arow) * lda + ((aseg ^ (arow & 7)) << 3);
  f32x4 ar0[8], ar1[8];  // two A-tiles in flight (static indexing only)
#define LA(u, arr, kt)                                                      \
  { const float* g_ = gA + (size_t)(u) * 64 * lda + (kt) * 64;              \
    arr[2 * (u)] = *reinterpret_cast<const f32x4*>(g_);                     \
    arr[2 * (u) + 1] = *reinterpret_cast<const f32x4*>(g_ + 4); }
#define WAu(u, arr, b)                                                      \
  { bf16x8 pk_;                                                             \
    _Pragma("unroll") for (int j_ = 0; j_ < 4; ++j_) {                      \
      pk_[j_] = (__bf16)arr[2 * (u)][j_];                                   \
      pk_[4 + j_] = (__bf16)arr[2 * (u) + 1][j_];                           \
    }                                                                       \
    *reinterpret_cast<bf16x8*>(                                             \
        &pool[(b) * 16384 + (arow + (u) * 64) * 64 + (aseg << 3)]) = pk_; }

  const int fr = lane & 15;
  const int fg = lane >> 4;
  const int fx = lane & 7;
  auto readA = [&](int b, int mi, int kf) -> bf16x8 {
    return *reinterpret_cast<const bf16x8*>(
        &pool[(b) * 16384 + (wm * 128 + mi * 16 + fr) * 64 +
              ((((kf << 2) + fg) ^ fx) << 3)]);
  };
  auto readB = [&](int b, int ni, int kf) -> bf16x8 {
    return *reinterpret_cast<const bf16x8*>(
        &pool[32768 + (b) * 16384 + (wn * 64 + ni * 16 + fr) * 64 +
              ((((kf << 2) + fg) ^ fx) << 3)]);
  };

  f32x4 acc[8][4];
#pragma unroll
  for (int i = 0; i < 8; ++i)
#pragma unroll
    for (int j = 0; j < 4; ++j) acc[i][j] = (f32x4){0.f, 0.f, 0.f, 0.f};
  bf16x8 bfr[4][2];

// VM: -1 none; 12 -> vmcnt(12)+lgkm(0); 0 -> vmcnt(0)+lgkm(0).
// lgkm pre-barrier publishes this phase's WA ds_writes to other waves.
#define PHASEF(b, q, READB, STAGES, VM)                                      \
  {                                                                          \
    bf16x8 a0_ = readA(b, 2 * (q), 0), a1_ = readA(b, 2 * (q), 1);           \
    bf16x8 a2_ = readA(b, 2 * (q) + 1, 0), a3_ = readA(b, 2 * (q) + 1, 1);   \
    if (READB) {                                                             \
      _Pragma("unroll") for (int ni = 0; ni < 4; ++ni) {                     \
        bfr[ni][0] = readB(b, ni, 0);                                        \
        bfr[ni][1] = readB(b, ni, 1);                                        \
      }                                                                      \
    }                                                                        \
    STAGES;                                                                  \
    if ((VM) == 12)                                                          \
      asm volatile("s_waitcnt vmcnt(12) lgkmcnt(0)" ::: "memory");           \
    if ((VM) == 0)                                                           \
      asm volatile("s_waitcnt vmcnt(0) lgkmcnt(0)" ::: "memory");            \
    __builtin_amdgcn_s_barrier();                                            \
    asm volatile("s_waitcnt lgkmcnt(0)" ::: "memory");                       \
    __builtin_amdgcn_sched_barrier(0);                                       \
    __builtin_amdgcn_s_setprio(1);                                           \
    _Pragma("unroll") for (int ni = 0; ni < 4; ++ni) {                       \
      acc[2 * (q)][ni] = __builtin_amdgcn_mfma_f32_16x16x32_bf16(            \
          a0_, bfr[ni][0], acc[2 * (q)][ni], 0, 0, 0);                       \
      acc[2 * (q) + 1][ni] = __builtin_amdgcn_mfma_f32_16x16x32_bf16(        \
          a2_, bfr[ni][0], acc[2 * (q) + 1][ni], 0, 0, 0);                   \
    }                                                                        \
    _Pragma("unroll") for (int ni = 0; ni < 4; ++ni) {                       \
      acc[2 * (q)][ni] = __builtin_amdgcn_mfma_f32_16x16x32_bf16(            \
          a1_, bfr[ni][1], acc[2 * (q)][ni], 0, 0, 0);                       \
      acc[2 * (q) + 1][ni] = __builtin_amdgcn_mfma_f32_16x16x32_bf16(        \
          a3_, bfr[ni][1], acc[2 * (q) + 1][ni], 0, 0, 0);                   \
    }                                                                        \
    __builtin_amdgcn_s_setprio(0);                                           \
    __builtin_amdgcn_s_barrier();                                            \
  }

  // prologue: LA(0)->ar0, LA(1)->ar1, B(0), B(1); WA(0); B(0) needs
  // vmcnt(4) (4 loads after SBb(0)); ar1 also drained by then (older).
  LA(0, ar0, 0) LA(1, ar0, 0) LA(2, ar0, 0) LA(3, ar0, 0)
  LA(0, ar1, 1) LA(1, ar1, 1) LA(2, ar1, 1) LA(3, ar1, 1)
  SBa(0, 0) SBb(0, 0) SBa(1, 1) SBb(1, 1)
  WAu(0, ar0, 0) WAu(1, ar0, 0) WAu(2, ar0, 0) WAu(3, ar0, 0)
  asm volatile("s_waitcnt vmcnt(4) lgkmcnt(0)" ::: "memory");
  __builtin_amdgcn_s_barrier();

  // Ledger (per-thread 16B-load units/phase): p0:4 p1:6 p2:2 p4:4 p5:4
  // p6:2 p7:2.  p3 target SBb(2i+1)@prev-p7 -> 12 after -> vmcnt(12).
  // p7 target SBa/SBb(2i+2)@p1,p2 -> 12 after -> vmcnt(12).
  // WA(2i+1)@p2,p3 <- LA@prev p4,p5 (gap>=4 phases ~1600cy > 900 HBM).
  // WA(2i+2)@p6,p7 <- LA@p0,p1 (gap 5-6 phases).
#pragma unroll
  for (int i = 0; i < 4; ++i) {
    const bool s2 = (i < 3);
    PHASEF(0, 0, true,  { if (s2) { LA(0, ar0, 2 * i + 2) LA(1, ar0, 2 * i + 2) } }, -1);
    PHASEF(0, 1, false, { if (s2) { LA(2, ar0, 2 * i + 2) LA(3, ar0, 2 * i + 2) SBa(2 * i + 2, 0) } }, -1);
    PHASEF(0, 2, false, { WAu(0, ar1, 1) WAu(1, ar1, 1) if (s2) SBb(2 * i + 2, 0) }, -1);
    PHASEF(0, 3, false, { WAu(2, ar1, 1) WAu(3, ar1, 1) }, s2 ? 12 : 0);
    PHASEF(1, 0, true,  { if (s2) { LA(0, ar1, 2 * i + 3) LA(1, ar1, 2 * i + 3) } }, -1);
    PHASEF(1, 1, false, { if (s2) { LA(2, ar1, 2 * i + 3) LA(3, ar1, 2 * i + 3) } }, -1);
    PHASEF(1, 2, false, { if (s2) { SBa(2 * i + 3, 1) WAu(0, ar0, 0) WAu(1, ar0, 0) } }, -1);
    PHASEF(1, 3, false, { if (s2) { SBb(2 * i + 3, 1) WAu(2, ar0, 0) WAu(3, ar0, 0) } }, s2 ? 12 : -1);
  }
#undef PHASEF
#undef SBa
#undef SBb
#undef LA
#undef WAu

  // ---- coalesced epilogue via LDS staging (R4/R11-verified, bf16) ----
  __syncthreads();
#pragma unroll
  for (int ni = 0; ni < 4; ++ni) {
    int cl = wn * 64 + ni * 16 + fr;
    float bc = bias[n0 + cl];
#pragma unroll
    for (int mi = 0; mi < 8; ++mi) {
      int rl = wm * 128 + mi * 16 + fg * 4;
#pragma unroll
      for (int r = 0; r < 4; ++r)
        pool[(rl + r) * 258 + cl] = f2bf(acc[mi][ni][r] + bc);
    }
  }
  __syncthreads();
#pragma unroll
  for (int it = 0; it < 16; ++it) {
    int idx = it * 512 + t;
    int row = idx >> 5, c8 = idx & 31;
    u16x8 v = *reinterpret_cast<const u16x8*>(&pool[row * 258 + c8 * 8]);
    *reinterpret_cast<u16x8*>(&C[(size_t)(m0 + row) * ldc + n0 + c8 * 8]) = v;
  }
}

// ---------------- 256x256 8-phase GEMM (R4/R11-verified) ------------------
// Used for the output projection (A = ctx bf16, C = f32).
template <typename CT>
__global__ __launch_bounds__(512, 2) void gemm256(
    const unsigned short* __restrict__ A, int lda,
    const unsigned short* __restrict__ BT,
    CT* __restrict__ C, int ldc,
    const float* __restrict__ bias, int NB) {
  __shared__ alignas(16) unsigned short pool[66048];  // 132096 B
  const int t = threadIdx.x;
  const int lane = t & 63;
  const int w = t >> 6;
  const int wm = w >> 2, wn = w & 3;

  const int nwg = gridDim.x;
  const int cpx = nwg >> 3;
  const int wg = (blockIdx.x & 7) * cpx + (blockIdx.x >> 3);
  const int n0 = (wg % NB) * 256;
  const int m0 = (wg / NB) * 256;

  const int sr = lane >> 3;
  const int sg = ((lane & 7) ^ sr) << 3;
  const unsigned short* gA = A + (size_t)(m0 + w * 8 + sr) * lda + sg;
  const unsigned short* gB = BT + (size_t)(n0 + w * 8 + sr) * 512 + sg;
  const int lw = w * 512;

#define STAGE_A(kt, h, b)                                                   \
  { const unsigned short* g_ = gA + (size_t)(h) * 128 * lda + (kt) * 64;    \
    unsigned short* l_ = &pool[(b) * 16384 + (h) * 8192 + lw];              \
    gl16(g_, l_); gl16(g_ + (size_t)64 * lda, l_ + 4096); }
#define STAGE_B(kt, h, b)                                                   \
  { const unsigned short* g_ = gB + (size_t)(h) * 128 * 512 + (kt) * 64;    \
    unsigned short* l_ = &pool[32768 + (b) * 16384 + (h) * 8192 + lw];      \
    gl16(g_, l_); gl16(g_ + (size_t)64 * 512, l_ + 4096); }

  const int fr = lane & 15;
  const int fg = lane >> 4;
  const int fx = lane & 7;
  auto readA = [&](int b, int mi, int kf) -> bf16x8 {
    return *reinterpret_cast<const bf16x8*>(
        &pool[(b) * 16384 + (wm * 128 + mi * 16 + fr) * 64 +
              ((((kf << 2) + fg) ^ fx) << 3)]);
  };
  auto readB = [&](int b, int ni, int kf) -> bf16x8 {
    return *reinterpret_cast<const bf16x8*>(
        &pool[32768 + (b) * 16384 + (wn * 64 + ni * 16 + fr) * 64 +
              ((((kf << 2) + fg) ^ fx) << 3)]);
  };

  f32x4 acc[8][4];
#pragma unroll
  for (int i = 0; i < 8; ++i)
#pragma unroll
    for (int j = 0; j < 4; ++j) acc[i][j] = (f32x4){0.f, 0.f, 0.f, 0.f};
  bf16x8 bfr[4][2];

#define PHASE(b, q, READB, STAGES, VM)                                       \
  {                                                                          \
    bf16x8 a0_ = readA(b, 2 * (q), 0), a1_ = readA(b, 2 * (q), 1);           \
    bf16x8 a2_ = readA(b, 2 * (q) + 1, 0), a3_ = readA(b, 2 * (q) + 1, 1);   \
    if (READB) {                                                             \
      _Pragma("unroll") for (int ni = 0; ni < 4; ++ni) {                     \
        bfr[ni][0] = readB(b, ni, 0);                                        \
        bfr[ni][1] = readB(b, ni, 1);                                        \
      }                                                                      \
    }                                                                        \
    STAGES;                                                                  \
    if ((VM) == 4) asm volatile("s_waitcnt vmcnt(4)" ::: "memory");          \
    if ((VM) == 0) asm volatile("s_waitcnt vmcnt(0)" ::: "memory");          \
    __builtin_amdgcn_s_barrier();                                            \
    asm volatile("s_waitcnt lgkmcnt(0)" ::: "memory");                       \
    __builtin_amdgcn_sched_barrier(0);                                       \
    __builtin_amdgcn_s_setprio(1);                                           \
    _Pragma("unroll") for (int ni = 0; ni < 4; ++ni) {                       \
      acc[2 * (q)][ni] = __builtin_amdgcn_mfma_f32_16x16x32_bf16(            \
          a0_, bfr[ni][0], acc[2 * (q)][ni], 0, 0, 0);                       \
      acc[2 * (q) + 1][ni] = __builtin_amdgcn_mfma_f32_16x16x32_bf16(        \
          a2_, bfr[ni][0], acc[2 * (q) + 1][ni], 0, 0, 0);                   \
    }                                                                        \
    _Pragma("unroll") for (int ni = 0; ni < 4; ++ni) {                       \
      acc[2 * (q)][ni] = __builtin_amdgcn_mfma_f32_16x16x32_bf16(            \
          a1_, bfr[ni][1], acc[2 * (q)][ni], 0, 0, 0);                       \
      acc[2 * (q) + 1][ni] = __builtin_amdgcn_mfma_f32_16x16x32_bf16(        \
          a3_, bfr[ni][1], acc[2 * (q) + 1][ni], 0, 0, 0);                   \
    }                                                                        \
    __builtin_amdgcn_s_setprio(0);                                           \
    __builtin_amdgcn_s_barrier();                                            \
  }

  STAGE_B(0, 0, 0); STAGE_B(0, 1, 0);
  STAGE_A(0, 0, 0); STAGE_A(0, 1, 0);
  STAGE_B(1, 0, 1); STAGE_B(1, 1, 1);
  asm volatile("s_waitcnt vmcnt(4)" ::: "memory");
  __builtin_amdgcn_s_barrier();

#pragma unroll
  for (int i = 0; i < 4; ++i) {
    const bool s2 = (i < 3);
    const int vmA = s2 ? 4 : 0;
    const int vmB = s2 ? 4 : 0;
    PHASE(0, 0, true,  { STAGE_A(2 * i + 1, 0, 1) }, -1);
    PHASE(0, 1, false, { STAGE_A(2 * i + 1, 1, 1) if (s2) STAGE_B(2 * i + 2, 0, 0) }, -1);
    PHASE(0, 2, false, { if (s2) STAGE_B(2 * i + 2, 1, 0) }, -1);
    PHASE(0, 3, false, {}, vmA);
    PHASE(1, 0, true,  { if (s2) STAGE_A(2 * i + 2, 0, 0) }, -1);
    PHASE(1, 1, false, { if (s2) STAGE_A(2 * i + 2, 1, 0) }, -1);
    PHASE(1, 2, false, { if (s2) STAGE_B(2 * i + 3, 0, 1) }, -1);
    PHASE(1, 3, false, { if (s2) STAGE_B(2 * i + 3, 1, 1) }, vmB);
  }
#undef PHASE
#undef STAGE_A
#undef STAGE_B

  // ---- coalesced epilogue via LDS staging (R4-verified) ----
  __syncthreads();
  if constexpr (sizeof(CT) == 2) {
#pragma unroll
    for (int ni = 0; ni < 4; ++ni) {
      int cl = wn * 64 + ni * 16 + fr;
      float bc = bias[n0 + cl];
#pragma unroll
      for (int mi = 0; mi < 8; ++mi) {
        int rl = wm * 128 + mi * 16 + fg * 4;
#pragma unroll
        for (int r = 0; r < 4; ++r)
          pool[(rl + r) * 258 + cl] = f2bf(acc[mi][ni][r] + bc);
      }
    }
    __syncthreads();
#pragma unroll
    for (int it = 0; it < 16; ++it) {
      int idx = it * 512 + t;
      int row = idx >> 5, c8 = idx & 31;
      u16x8 v = *reinterpret_cast<const u16x8*>(&pool[row * 258 + c8 * 8]);
      *reinterpret_cast<u16x8*>(&C[(size_t)(m0 + row) * ldc + n0 + c8 * 8]) = v;
    }
  } else {
    float* stf = reinterpret_cast<float*>(pool);
#pragma unroll
    for (int h = 0; h < 2; ++h) {
      if (wm == h) {
#pragma unroll
        for (int ni = 0; ni < 4; ++ni) {
          int cl = wn * 64 + ni * 16 + fr;
          float bc = bias[n0 + cl];
#pragma unroll
          for (int mi = 0; mi < 8; ++mi) {
            int rl = mi * 16 + fg * 4;
#pragma unroll
            for (int r = 0; r < 4; ++r)
              stf[(rl + r) * 258 + cl] = acc[mi][ni][r] + bc;
          }
        }
      }
      __syncthreads();
#pragma unroll
      for (int it = 0; it < 16; ++it) {
        int idx = it * 512 + t;
        int row = idx >> 6, c4 = idx & 63;
        f32x4 v = *reinterpret_cast<const f32x4*>(&stf[row * 258 + c4 * 4]);
        *reinterpret_cast<f32x4*>(
            &C[(size_t)(m0 + h * 128 + row) * ldc + n0 + c4 * 4]) = v;
      }
      __syncthreads();
    }
  }
}

// ---------------- MFMA attention, double-buffered head pipeline -----------
// (R11-verified.) Block = 256 thr owns 128 rows; wave does 2 windows.
// LDS: K 2x8192 | V 2x8192 | ps 1024 = 33792 shorts.
__global__ __launch_bounds__(256) void attn2(unsigned short* __restrict__ QKV) {
  __shared__ alignas(16) unsigned short sh[33792];
  const int VS = 16384, PS = 32768;
  const int t = threadIdx.x;
  const int lane = t & 63;
  const int w = t >> 6;
  const int fr = lane & 15, fg = lane >> 4, fx = lane & 7;
  const int sr = lane >> 3;
  const int sgx = ((lane & 7) ^ sr) << 3;
  const int sgl = (lane & 7) << 3;
  const size_t m0r = (size_t)blockIdx.x * 128;

#define SK2(h, b)                                                            \
  _Pragma("unroll") for (int u = 0; u < 4; ++u) {                            \
    const int r0 = u * 32 + w * 8;                                           \
    gl16(QKV + (m0r + r0 + sr) * 1536 + 512 + (h) * 64 + sgx,                \
         &sh[(b) * 8192 + r0 * 64]);                                         \
  }
#define SV2(h, b)                                                            \
  _Pragma("unroll") for (int u = 0; u < 4; ++u) {                            \
    const int r0 = u * 32 + w * 8;                                           \
    gl16(QKV + (m0r + r0 + sr) * 1536 + 1024 + (h) * 64 + sgl,               \
         &sh[VS + (b) * 8192 + r0 * 64]);                                    \
  }

  SK2(0, 0) SV2(0, 0)
  asm volatile("s_waitcnt vmcnt(0)" ::: "memory");
  __syncthreads();

  for (int h = 0; h < 8; ++h) {
    const int b = h & 1;
    u16x8 q[2][2];
#pragma unroll
    for (int ww = 0; ww < 2; ++ww) {
      const int wi = w * 2 + ww;
      const unsigned short* qrow = QKV + (m0r + wi * 16 + fr) * 1536 + h * 64;
      q[ww][0] = *reinterpret_cast<const u16x8*>(qrow + fg * 8);
      q[ww][1] = *reinterpret_cast<const u16x8*>(qrow + 32 + fg * 8);
    }
    if (h < 7) { SK2(h + 1, b ^ 1) SV2(h + 1, b ^ 1) }

#pragma unroll
    for (int ww = 0; ww < 2; ++ww) {
      const int wi = w * 2 + ww;
      f32x4 s = (f32x4){0.f, 0.f, 0.f, 0.f};
      {
        bf16x8 kf_ = *reinterpret_cast<const bf16x8*>(
            &sh[b * 8192 + (wi * 16 + fr) * 64 + ((fg ^ fx) << 3)]);
        s = __builtin_amdgcn_mfma_f32_16x16x32_bf16(
            kf_, __builtin_bit_cast(bf16x8, q[ww][0]), s, 0, 0, 0);
        kf_ = *reinterpret_cast<const bf16x8*>(
            &sh[b * 8192 + (wi * 16 + fr) * 64 + (((4 + fg) ^ fx) << 3)]);
        s = __builtin_amdgcn_mfma_f32_16x16x32_bf16(
            kf_, __builtin_bit_cast(bf16x8, q[ww][1]), s, 0, 0, 0);
      }
      u16x4 pfu;
#pragma unroll
      for (int r = 0; r < 4; ++r)
        pfu[r] = f2bf(1.0f / (1.0f + __expf(-s[r] * 0.125f)));
      *reinterpret_cast<u16x4*>(&sh[PS + w * 256 + fr * 16 + fg * 4]) = pfu;
      u16x8 pbu = (u16x8){0, 0, 0, 0, 0, 0, 0, 0};
      if (fg < 2)
        pbu = *reinterpret_cast<const u16x8*>(&sh[PS + w * 256 + fr * 16 + fg * 8]);
      bf16x8 pb = __builtin_bit_cast(bf16x8, pbu);
#pragma unroll
      for (int dc = 0; dc < 4; ++dc) {
        u16x8 vau;
#pragma unroll
        for (int j = 0; j < 8; ++j)
          vau[j] = sh[VS + b * 8192 + (wi * 16 + (fg & 1) * 8 + j) * 64 + dc * 16 + fr];
        f32x4 c = __builtin_amdgcn_mfma_f32_16x16x32_bf16(
            __builtin_bit_cast(bf16x8, vau), pb, (f32x4){0.f, 0.f, 0.f, 0.f},
            0, 0, 0);
        u16x4 o;
#pragma unroll
        for (int r = 0; r < 4; ++r) o[r] = f2bf(c[r]);
        *reinterpret_cast<u16x4*>(
            &QKV[(m0r + wi * 16 + fr) * 1536 + 1024 + h * 64 + dc * 16 + fg * 4]) = o;
      }
    }
    asm volatile("s_waitcnt vmcnt(8)" ::: "memory");
    __syncthreads();
  }
#undef SK2
#undef SV2
}

// --------------------------------------------------------------------------
extern "C" void kernel_launch(void* const* d_in, const int* in_sizes, int n_in,
                              void* d_out, int out_size, void* d_ws, size_t ws_size,
                              hipStream_t stream) {
  const float* x  = (const float*)d_in[0];
  const float* Wq = (const float*)d_in[1];
  const float* bq = (const float*)d_in[2];
  const float* Wk = (const float*)d_in[3];
  const float* bk = (const float*)d_in[4];
  const float* Wv = (const float*)d_in[5];
  const float* bv = (const float*)d_in[6];
  const float* Wo = (const float*)d_in[7];
  const float* bo = (const float*)d_in[8];
  float* out = (float*)d_out;

  const int M = 65536;
  char* ws = (char*)d_ws;
  unsigned short* WT = (unsigned short*)ws;                  // [2048][512] bf16
  float* biasc = (float*)(ws + (size_t)2048 * 512 * 2);      // [1536]
  const long long prep_bytes = (long long)2048 * 512 * 2 + 8192;

  prep_wt<<<dim3(8, 8, 4), 256, 0, stream>>>(Wq, Wk, Wv, Wo, WT);
  prep_bias<<<6, 256, 0, stream>>>(bq, bk, bv, biasc);

  // per-chunk: QKV rows*1536*2 = rows*3072 B (no Xb anymore)
  long long avail = (long long)ws_size - prep_bytes;
  int chunk_rows = 65536;
  while (chunk_rows > 2048 && (long long)chunk_rows * 3072 > avail) chunk_rows >>= 1;
  const int nchunks = M / chunk_rows;

  unsigned short* QKV = (unsigned short*)(ws + prep_bytes);

  for (int c = 0; c < nchunks; ++c) {
    const size_t row0 = (size_t)c * chunk_rows;
    const int mt = chunk_rows / 256;
    gemm256_f32a<<<mt * 6, 512, 0, stream>>>(
        x + row0 * 512, 512, WT, QKV, 1536, biasc, 6);
    attn2<<<chunk_rows / 128, 256, 0, stream>>>(QKV);
    gemm256<float><<<mt * 2, 512, 0, stream>>>(
        QKV + 1024, 1536, WT + (size_t)1536 * 512, out + row0 * 512, 512, bo, 2);
  }
}

// Round 13
// 294.276 us; speedup vs baseline: 1.4285x; 1.4285x over previous
//
#include <hip/hip_runtime.h>
#include <hip/hip_bf16.h>

typedef float f32x4 __attribute__((ext_vector_type(4)));
typedef __bf16 bf16x8 __attribute__((ext_vector_type(8)));
typedef unsigned short u16x4 __attribute__((ext_vector_type(4)));
typedef unsigned short u16x8 __attribute__((ext_vector_type(8)));

__device__ __forceinline__ unsigned short f2bf(float f) {
  union { float f; unsigned u; } x; x.f = f;
  unsigned r = x.u + 0x7FFFu + ((x.u >> 16) & 1u);
  return (unsigned short)(r >> 16);
}

__device__ __forceinline__ void gl16(const void* g, void* l) {
  __builtin_amdgcn_global_load_lds(
      (const __attribute__((address_space(1))) unsigned*)g,
      (__attribute__((address_space(3))) unsigned*)l, 16, 0, 0);
}

// ---------------- prep: W[k][n] f32 -> WT[n][k] bf16 (4 mats: q,k,v,o) ----
__global__ __launch_bounds__(256) void prep_wt(const float* __restrict__ Wq,
                                               const float* __restrict__ Wk,
                                               const float* __restrict__ Wv,
                                               const float* __restrict__ Wo,
                                               unsigned short* __restrict__ WT) {
  __shared__ unsigned short ts[64][65];
  const float* W = (blockIdx.z == 0) ? Wq : (blockIdx.z == 1) ? Wk
                   : (blockIdx.z == 2) ? Wv : Wo;
  const int t = threadIdx.x;
  const int kbase = blockIdx.y * 64;
  const int nbase = blockIdx.x * 64;
  for (int i = 0; i < 16; ++i) {
    int idx = i * 256 + t;
    int r = idx >> 6, c = idx & 63;
    ts[r][c] = f2bf(W[(size_t)(kbase + r) * 512 + nbase + c]);
  }
  __syncthreads();
  unsigned short* dst = WT + (size_t)blockIdx.z * 512 * 512;
  for (int i = 0; i < 16; ++i) {
    int idx = i * 256 + t;
    int nn = idx >> 6, kk = idx & 63;
    dst[(size_t)(nbase + nn) * 512 + kbase + kk] = ts[kk][nn];
  }
}

__global__ void prep_bias(const float* __restrict__ bq, const float* __restrict__ bk,
                          const float* __restrict__ bv, float* __restrict__ biasc) {
  int i = blockIdx.x * 256 + threadIdx.x;
  if (i < 512) biasc[i] = bq[i];
  else if (i < 1024) biasc[i] = bk[i - 512];
  else if (i < 1536) biasc[i] = bv[i - 1024];
}

// ---------------- convert X fp32 -> bf16 (streaming) ----------------------
__global__ __launch_bounds__(256) void convert_x(const float* __restrict__ x,
                                                 unsigned short* __restrict__ xb,
                                                 long long n8) {
  long long i = (long long)blockIdx.x * 256 + threadIdx.x;
  const long long stride = (long long)gridDim.x * 256;
  for (; i < n8; i += stride) {
    f32x4 a = *reinterpret_cast<const f32x4*>(&x[i * 8]);
    f32x4 b = *reinterpret_cast<const f32x4*>(&x[i * 8 + 4]);
    u16x8 o;
    o[0] = f2bf(a[0]); o[1] = f2bf(a[1]); o[2] = f2bf(a[2]); o[3] = f2bf(a[3]);
    o[4] = f2bf(b[0]); o[5] = f2bf(b[1]); o[6] = f2bf(b[2]); o[7] = f2bf(b[3]);
    *reinterpret_cast<u16x8*>(&xb[i * 8]) = o;
  }
}

// ---------------- 256x256 GEMM, 4 merged phases (32 MFMA/barrier) ---------
// A bf16 [M][lda], BT bf16 [N][512], K=512 (8 K-tiles of BK=64).
// 512 thr = 8 waves (2m x 4n). Same staging/ledger as the R11 8-phase
// version (prologue leaves B(t+1) in flight; vmcnt(4) at P1/P3 ends);
// phases merged pairwise -> half the barriers per block (64 -> 32).
template <typename CT>
__global__ __launch_bounds__(512, 2) void gemm256(
    const unsigned short* __restrict__ A, int lda,
    const unsigned short* __restrict__ BT,
    CT* __restrict__ C, int ldc,
    const float* __restrict__ bias, int NB) {
  __shared__ alignas(16) unsigned short pool[66048];  // 132096 B
  const int t = threadIdx.x;
  const int lane = t & 63;
  const int w = t >> 6;
  const int wm = w >> 2, wn = w & 3;

  const int nwg = gridDim.x;
  const int cpx = nwg >> 3;
  const int wg = (blockIdx.x & 7) * cpx + (blockIdx.x >> 3);
  const int n0 = (wg % NB) * 256;
  const int m0 = (wg / NB) * 256;

  const int sr = lane >> 3;
  const int sg = ((lane & 7) ^ sr) << 3;
  const unsigned short* gA = A + (size_t)(m0 + w * 8 + sr) * lda + sg;
  const unsigned short* gB = BT + (size_t)(n0 + w * 8 + sr) * 512 + sg;
  const int lw = w * 512;

#define STAGE_A(kt, h, b)                                                   \
  { const unsigned short* g_ = gA + (size_t)(h) * 128 * lda + (kt) * 64;    \
    unsigned short* l_ = &pool[(b) * 16384 + (h) * 8192 + lw];              \
    gl16(g_, l_); gl16(g_ + (size_t)64 * lda, l_ + 4096); }
#define STAGE_B(kt, h, b)                                                   \
  { const unsigned short* g_ = gB + (size_t)(h) * 128 * 512 + (kt) * 64;    \
    unsigned short* l_ = &pool[32768 + (b) * 16384 + (h) * 8192 + lw];      \
    gl16(g_, l_); gl16(g_ + (size_t)64 * 512, l_ + 4096); }

  const int fr = lane & 15;
  const int fg = lane >> 4;
  const int fx = lane & 7;
  auto readA = [&](int b, int mi, int kf) -> bf16x8 {
    return *reinterpret_cast<const bf16x8*>(
        &pool[(b) * 16384 + (wm * 128 + mi * 16 + fr) * 64 +
              ((((kf << 2) + fg) ^ fx) << 3)]);
  };
  auto readB = [&](int b, int ni, int kf) -> bf16x8 {
    return *reinterpret_cast<const bf16x8*>(
        &pool[32768 + (b) * 16384 + (wn * 64 + ni * 16 + fr) * 64 +
              ((((kf << 2) + fg) ^ fx) << 3)]);
  };

  f32x4 acc[8][4];
#pragma unroll
  for (int i = 0; i < 8; ++i)
#pragma unroll
    for (int j = 0; j < 4; ++j) acc[i][j] = (f32x4){0.f, 0.f, 0.f, 0.f};
  bf16x8 afr[8];
  bf16x8 bfr[4][2];

// merged phase: 8 A-frag reads (mi quad 4h..4h+3, both kf) | optional 8 B
// reads | stage issue | [vmcnt] | bar | lgkm0 | 32 MFMA (kf0 then kf1 --
// dependent pairs 16 apart) | bar.
#define PHASE2(b, h, READB, STAGES, VM)                                      \
  {                                                                          \
    afr[0] = readA(b, 4 * (h) + 0, 0); afr[1] = readA(b, 4 * (h) + 0, 1);    \
    afr[2] = readA(b, 4 * (h) + 1, 0); afr[3] = readA(b, 4 * (h) + 1, 1);    \
    afr[4] = readA(b, 4 * (h) + 2, 0); afr[5] = readA(b, 4 * (h) + 2, 1);    \
    afr[6] = readA(b, 4 * (h) + 3, 0); afr[7] = readA(b, 4 * (h) + 3, 1);    \
    if (READB) {                                                             \
      _Pragma("unroll") for (int ni = 0; ni < 4; ++ni) {                     \
        bfr[ni][0] = readB(b, ni, 0);                                        \
        bfr[ni][1] = readB(b, ni, 1);                                        \
      }                                                                      \
    }                                                                        \
    STAGES;                                                                  \
    if ((VM) == 4) asm volatile("s_waitcnt vmcnt(4)" ::: "memory");          \
    if ((VM) == 0) asm volatile("s_waitcnt vmcnt(0)" ::: "memory");          \
    __builtin_amdgcn_s_barrier();                                            \
    asm volatile("s_waitcnt lgkmcnt(0)" ::: "memory");                       \
    __builtin_amdgcn_sched_barrier(0);                                       \
    __builtin_amdgcn_s_setprio(1);                                           \
    _Pragma("unroll") for (int ni = 0; ni < 4; ++ni)                         \
      _Pragma("unroll") for (int m4 = 0; m4 < 4; ++m4)                       \
        acc[4 * (h) + m4][ni] = __builtin_amdgcn_mfma_f32_16x16x32_bf16(     \
            afr[2 * m4], bfr[ni][0], acc[4 * (h) + m4][ni], 0, 0, 0);        \
    _Pragma("unroll") for (int ni = 0; ni < 4; ++ni)                         \
      _Pragma("unroll") for (int m4 = 0; m4 < 4; ++m4)                       \
        acc[4 * (h) + m4][ni] = __builtin_amdgcn_mfma_f32_16x16x32_bf16(     \
            afr[2 * m4 + 1], bfr[ni][1], acc[4 * (h) + m4][ni], 0, 0, 0);    \
    __builtin_amdgcn_s_setprio(0);                                           \
    __builtin_amdgcn_s_barrier();                                            \
  }

  // prologue: t0 fully + t1.B; vmcnt(4) leaves t1.B (4 loads) in flight
  STAGE_B(0, 0, 0); STAGE_B(0, 1, 0);
  STAGE_A(0, 0, 0); STAGE_A(0, 1, 0);
  STAGE_B(1, 0, 1); STAGE_B(1, 1, 1);
  asm volatile("s_waitcnt vmcnt(4)" ::: "memory");
  __builtin_amdgcn_s_barrier();

  // Ledger per iter i (buf0=tile 2i, buf1=tile 2i+1), 4-unit STAGE pairs:
  //  P0 in: B(2i+1)=4; +A(2i+1)=8.
  //  P1 +B(2i+2)=12; vmcnt(4) -> buf1 (A+B of 2i+1) landed, B(2i+2) flies.
  //  P2 +A(2i+2)=8.
  //  P3 +B(2i+3)=12; vmcnt(4) -> buf0 (2i+2) landed, B(2i+3) flies.
  // Overwrite legality: B regions re-staged only after their READB phase's
  // end barrier (B held in regs); A regions after their tile's last phase.
#pragma unroll
  for (int i = 0; i < 4; ++i) {
    const bool s2 = (i < 3);
    PHASE2(0, 0, true,  { STAGE_A(2 * i + 1, 0, 1) STAGE_A(2 * i + 1, 1, 1) }, -1);
    PHASE2(0, 1, false, { if (s2) { STAGE_B(2 * i + 2, 0, 0) STAGE_B(2 * i + 2, 1, 0) } }, s2 ? 4 : 0);
    PHASE2(1, 0, true,  { if (s2) { STAGE_A(2 * i + 2, 0, 0) STAGE_A(2 * i + 2, 1, 0) } }, -1);
    PHASE2(1, 1, false, { if (s2) { STAGE_B(2 * i + 3, 0, 1) STAGE_B(2 * i + 3, 1, 1) } }, s2 ? 4 : 0);
  }
#undef PHASE2
#undef STAGE_A
#undef STAGE_B

  // ---- coalesced epilogue via LDS staging (R4/R11-verified) ----
  __syncthreads();
  if constexpr (sizeof(CT) == 2) {
#pragma unroll
    for (int ni = 0; ni < 4; ++ni) {
      int cl = wn * 64 + ni * 16 + fr;
      float bc = bias[n0 + cl];
#pragma unroll
      for (int mi = 0; mi < 8; ++mi) {
        int rl = wm * 128 + mi * 16 + fg * 4;
#pragma unroll
        for (int r = 0; r < 4; ++r)
          pool[(rl + r) * 258 + cl] = f2bf(acc[mi][ni][r] + bc);
      }
    }
    __syncthreads();
#pragma unroll
    for (int it = 0; it < 16; ++it) {
      int idx = it * 512 + t;
      int row = idx >> 5, c8 = idx & 31;
      u16x8 v = *reinterpret_cast<const u16x8*>(&pool[row * 258 + c8 * 8]);
      *reinterpret_cast<u16x8*>(&C[(size_t)(m0 + row) * ldc + n0 + c8 * 8]) = v;
    }
  } else {
    float* stf = reinterpret_cast<float*>(pool);
#pragma unroll
    for (int h = 0; h < 2; ++h) {
      if (wm == h) {
#pragma unroll
        for (int ni = 0; ni < 4; ++ni) {
          int cl = wn * 64 + ni * 16 + fr;
          float bc = bias[n0 + cl];
#pragma unroll
          for (int mi = 0; mi < 8; ++mi) {
            int rl = mi * 16 + fg * 4;
#pragma unroll
            for (int r = 0; r < 4; ++r)
              stf[(rl + r) * 258 + cl] = acc[mi][ni][r] + bc;
          }
        }
      }
      __syncthreads();
#pragma unroll
      for (int it = 0; it < 16; ++it) {
        int idx = it * 512 + t;
        int row = idx >> 6, c4 = idx & 63;
        f32x4 v = *reinterpret_cast<const f32x4*>(&stf[row * 258 + c4 * 4]);
        *reinterpret_cast<f32x4*>(
            &C[(size_t)(m0 + h * 128 + row) * ldc + n0 + c4 * 4]) = v;
      }
      __syncthreads();
    }
  }
}

// ---------------- MFMA attention, double-buffered head pipeline -----------
// (R11-verified.) Block = 256 thr owns 128 rows; wave does 2 windows.
// LDS: K 2x8192 | V 2x8192 | ps 1024 = 33792 shorts.
__global__ __launch_bounds__(256) void attn2(unsigned short* __restrict__ QKV) {
  __shared__ alignas(16) unsigned short sh[33792];
  const int VS = 16384, PS = 32768;
  const int t = threadIdx.x;
  const int lane = t & 63;
  const int w = t >> 6;
  const int fr = lane & 15, fg = lane >> 4, fx = lane & 7;
  const int sr = lane >> 3;
  const int sgx = ((lane & 7) ^ sr) << 3;
  const int sgl = (lane & 7) << 3;
  const size_t m0r = (size_t)blockIdx.x * 128;

#define SK2(h, b)                                                            \
  _Pragma("unroll") for (int u = 0; u < 4; ++u) {                            \
    const int r0 = u * 32 + w * 8;                                           \
    gl16(QKV + (m0r + r0 + sr) * 1536 + 512 + (h) * 64 + sgx,                \
         &sh[(b) * 8192 + r0 * 64]);                                         \
  }
#define SV2(h, b)                                                            \
  _Pragma("unroll") for (int u = 0; u < 4; ++u) {                            \
    const int r0 = u * 32 + w * 8;                                           \
    gl16(QKV + (m0r + r0 + sr) * 1536 + 1024 + (h) * 64 + sgl,               \
         &sh[VS + (b) * 8192 + r0 * 64]);                                    \
  }

  SK2(0, 0) SV2(0, 0)
  asm volatile("s_waitcnt vmcnt(0)" ::: "memory");
  __syncthreads();

  for (int h = 0; h < 8; ++h) {
    const int b = h & 1;
    u16x8 q[2][2];
#pragma unroll
    for (int ww = 0; ww < 2; ++ww) {
      const int wi = w * 2 + ww;
      const unsigned short* qrow = QKV + (m0r + wi * 16 + fr) * 1536 + h * 64;
      q[ww][0] = *reinterpret_cast<const u16x8*>(qrow + fg * 8);
      q[ww][1] = *reinterpret_cast<const u16x8*>(qrow + 32 + fg * 8);
    }
    if (h < 7) { SK2(h + 1, b ^ 1) SV2(h + 1, b ^ 1) }

#pragma unroll
    for (int ww = 0; ww < 2; ++ww) {
      const int wi = w * 2 + ww;
      f32x4 s = (f32x4){0.f, 0.f, 0.f, 0.f};
      {
        bf16x8 kf_ = *reinterpret_cast<const bf16x8*>(
            &sh[b * 8192 + (wi * 16 + fr) * 64 + ((fg ^ fx) << 3)]);
        s = __builtin_amdgcn_mfma_f32_16x16x32_bf16(
            kf_, __builtin_bit_cast(bf16x8, q[ww][0]), s, 0, 0, 0);
        kf_ = *reinterpret_cast<const bf16x8*>(
            &sh[b * 8192 + (wi * 16 + fr) * 64 + (((4 + fg) ^ fx) << 3)]);
        s = __builtin_amdgcn_mfma_f32_16x16x32_bf16(
            kf_, __builtin_bit_cast(bf16x8, q[ww][1]), s, 0, 0, 0);
      }
      u16x4 pfu;
#pragma unroll
      for (int r = 0; r < 4; ++r)
        pfu[r] = f2bf(1.0f / (1.0f + __expf(-s[r] * 0.125f)));
      *reinterpret_cast<u16x4*>(&sh[PS + w * 256 + fr * 16 + fg * 4]) = pfu;
      u16x8 pbu = (u16x8){0, 0, 0, 0, 0, 0, 0, 0};
      if (fg < 2)
        pbu = *reinterpret_cast<const u16x8*>(&sh[PS + w * 256 + fr * 16 + fg * 8]);
      bf16x8 pb = __builtin_bit_cast(bf16x8, pbu);
#pragma unroll
      for (int dc = 0; dc < 4; ++dc) {
        u16x8 vau;
#pragma unroll
        for (int j = 0; j < 8; ++j)
          vau[j] = sh[VS + b * 8192 + (wi * 16 + (fg & 1) * 8 + j) * 64 + dc * 16 + fr];
        f32x4 c = __builtin_amdgcn_mfma_f32_16x16x32_bf16(
            __builtin_bit_cast(bf16x8, vau), pb, (f32x4){0.f, 0.f, 0.f, 0.f},
            0, 0, 0);
        u16x4 o;
#pragma unroll
        for (int r = 0; r < 4; ++r) o[r] = f2bf(c[r]);
        *reinterpret_cast<u16x4*>(
            &QKV[(m0r + wi * 16 + fr) * 1536 + 1024 + h * 64 + dc * 16 + fg * 4]) = o;
      }
    }
    asm volatile("s_waitcnt vmcnt(8)" ::: "memory");
    __syncthreads();
  }
#undef SK2
#undef SV2
}

// --------------------------------------------------------------------------
extern "C" void kernel_launch(void* const* d_in, const int* in_sizes, int n_in,
                              void* d_out, int out_size, void* d_ws, size_t ws_size,
                              hipStream_t stream) {
  const float* x  = (const float*)d_in[0];
  const float* Wq = (const float*)d_in[1];
  const float* bq = (const float*)d_in[2];
  const float* Wk = (const float*)d_in[3];
  const float* bk = (const float*)d_in[4];
  const float* Wv = (const float*)d_in[5];
  const float* bv = (const float*)d_in[6];
  const float* Wo = (const float*)d_in[7];
  const float* bo = (const float*)d_in[8];
  float* out = (float*)d_out;

  const int M = 65536;
  char* ws = (char*)d_ws;
  unsigned short* WT = (unsigned short*)ws;                  // [2048][512] bf16
  float* biasc = (float*)(ws + (size_t)2048 * 512 * 2);      // [1536]
  const long long prep_bytes = (long long)2048 * 512 * 2 + 8192;

  prep_wt<<<dim3(8, 8, 4), 256, 0, stream>>>(Wq, Wk, Wv, Wo, WT);
  prep_bias<<<6, 256, 0, stream>>>(bq, bk, bv, biasc);

  // per-chunk: Xb rows*512*2 + QKV rows*1536*2 = rows*4096 B
  long long avail = (long long)ws_size - prep_bytes;
  int chunk_rows = 65536;
  while (chunk_rows > 2048 && (long long)chunk_rows * 4096 > avail) chunk_rows >>= 1;
  const int nchunks = M / chunk_rows;

  unsigned short* Xb  = (unsigned short*)(ws + prep_bytes);
  unsigned short* QKV = Xb + (size_t)chunk_rows * 512;

  for (int c = 0; c < nchunks; ++c) {
    const size_t row0 = (size_t)c * chunk_rows;
    const int mt = chunk_rows / 256;
    convert_x<<<2048, 256, 0, stream>>>(x + row0 * 512, Xb,
                                        (long long)chunk_rows * 64);
    gemm256<unsigned short><<<mt * 6, 512, 0, stream>>>(
        Xb, 512, WT, QKV, 1536, biasc, 6);
    attn2<<<chunk_rows / 128, 256, 0, stream>>>(QKV);
    gemm256<float><<<mt * 2, 512, 0, stream>>>(
        QKV + 1024, 1536, WT + (size_t)1536 * 512, out + row0 * 512, 512, bo, 2);
  }
}

// Round 14
// 294.192 us; speedup vs baseline: 1.4289x; 1.0003x over previous
//
#include <hip/hip_runtime.h>
#include <hip/hip_bf16.h>

typedef float f32x4 __attribute__((ext_vector_type(4)));
typedef __bf16 bf16x8 __attribute__((ext_vector_type(8)));
typedef unsigned short u16x4 __attribute__((ext_vector_type(4)));
typedef unsigned short u16x8 __attribute__((ext_vector_type(8)));

__device__ __forceinline__ unsigned short f2bf(float f) {
  union { float f; unsigned u; } x; x.f = f;
  unsigned r = x.u + 0x7FFFu + ((x.u >> 16) & 1u);
  return (unsigned short)(r >> 16);
}

__device__ __forceinline__ void gl16(const void* g, void* l) {
  __builtin_amdgcn_global_load_lds(
      (const __attribute__((address_space(1))) unsigned*)g,
      (__attribute__((address_space(3))) unsigned*)l, 16, 0, 0);
}

// ---------------- prep: W[k][n] f32 -> WT[n][k] bf16 (4 mats: q,k,v,o) ----
__global__ __launch_bounds__(256) void prep_wt(const float* __restrict__ Wq,
                                               const float* __restrict__ Wk,
                                               const float* __restrict__ Wv,
                                               const float* __restrict__ Wo,
                                               unsigned short* __restrict__ WT) {
  __shared__ unsigned short ts[64][65];
  const float* W = (blockIdx.z == 0) ? Wq : (blockIdx.z == 1) ? Wk
                   : (blockIdx.z == 2) ? Wv : Wo;
  const int t = threadIdx.x;
  const int kbase = blockIdx.y * 64;
  const int nbase = blockIdx.x * 64;
  for (int i = 0; i < 16; ++i) {
    int idx = i * 256 + t;
    int r = idx >> 6, c = idx & 63;
    ts[r][c] = f2bf(W[(size_t)(kbase + r) * 512 + nbase + c]);
  }
  __syncthreads();
  unsigned short* dst = WT + (size_t)blockIdx.z * 512 * 512;
  for (int i = 0; i < 16; ++i) {
    int idx = i * 256 + t;
    int nn = idx >> 6, kk = idx & 63;
    dst[(size_t)(nbase + nn) * 512 + kbase + kk] = ts[kk][nn];
  }
}

__global__ void prep_bias(const float* __restrict__ bq, const float* __restrict__ bk,
                          const float* __restrict__ bv, float* __restrict__ biasc) {
  int i = blockIdx.x * 256 + threadIdx.x;
  if (i < 512) biasc[i] = bq[i];
  else if (i < 1024) biasc[i] = bk[i - 512];
  else if (i < 1536) biasc[i] = bv[i - 1024];
}

// ---------------- convert X fp32 -> bf16 (streaming) ----------------------
__global__ __launch_bounds__(256) void convert_x(const float* __restrict__ x,
                                                 unsigned short* __restrict__ xb,
                                                 long long n8) {
  long long i = (long long)blockIdx.x * 256 + threadIdx.x;
  const long long stride = (long long)gridDim.x * 256;
  for (; i < n8; i += stride) {
    f32x4 a = *reinterpret_cast<const f32x4*>(&x[i * 8]);
    f32x4 b = *reinterpret_cast<const f32x4*>(&x[i * 8 + 4]);
    u16x8 o;
    o[0] = f2bf(a[0]); o[1] = f2bf(a[1]); o[2] = f2bf(a[2]); o[3] = f2bf(a[3]);
    o[4] = f2bf(b[0]); o[5] = f2bf(b[1]); o[6] = f2bf(b[2]); o[7] = f2bf(b[3]);
    *reinterpret_cast<u16x8*>(&xb[i * 8]) = o;
  }
}

// ---------------- 128x128 GEMM, BK=32, 1 barrier/phase, 4 blocks/CU -------
// A bf16 [M][lda], BT bf16 [N][512], K=512 (16 K-tiles of BK=32).
// 256 thr = 4 waves (2m x 2n), wave-tile 64x64, acc[4][4] (64 VGPR).
// LDS 33KB: A dbuf 2x4096 | B dbuf 2x4096 shorts; epilogue reuses pool.
// Phase t: issue stage(t+1) -> 8 ds_read frags(buf t) -> lgkm0 -> 16 MFMA
// -> vmcnt(0) (covered by ~reads+MFMA; residue filled by 3 other blocks)
// -> barrier. Barrier-exit proves all waves' stage(t+1) landed.
// Swizzle (64B rows, 4 granules): slot = g ^ ((row>>1)&3) -> 2-way free
// on frag reads; staged via inverse-swizzled global src (linear LDS dest).
template <typename CT>
__global__ __launch_bounds__(256, 4) void gemm128(
    const unsigned short* __restrict__ A, int lda,
    const unsigned short* __restrict__ BT,
    CT* __restrict__ C, int ldc,
    const float* __restrict__ bias, int NB) {
  __shared__ alignas(16) unsigned short pool[16640];  // 33280 B
  const int t = threadIdx.x;
  const int lane = t & 63;
  const int w = t >> 6;                 // 0..3
  const int wm = w >> 1, wn = w & 1;

  const int nwg = gridDim.x;
  const int cpx = nwg >> 3;
  const int wg = (blockIdx.x & 7) * cpx + (blockIdx.x >> 3);
  const int n0 = (wg % NB) * 128;
  const int m0 = (wg / NB) * 128;

  // staging: wave w covers rows w*32..w*32+31 (2 gl16 of 16 rows each);
  // lane -> row lane>>2, linear granule lane&3; src granule inverse-swizzled
  const int sgr = lane >> 2;
  const int sgc = ((lane & 3) ^ ((lane >> 3) & 3)) << 3;
  const unsigned short* gA = A + (size_t)(m0 + w * 32 + sgr) * lda + sgc;
  const unsigned short* gB = BT + (size_t)(n0 + w * 32 + sgr) * 512 + sgc;
  const int lw = w * 1024;

#define SA(kt, b)                                                           \
  { const unsigned short* g_ = gA + (kt) * 32;                              \
    gl16(g_, &pool[(b) * 4096 + lw]);                                       \
    gl16(g_ + (size_t)16 * lda, &pool[(b) * 4096 + lw + 512]); }
#define SB(kt, b)                                                           \
  { const unsigned short* g_ = gB + (kt) * 32;                              \
    gl16(g_, &pool[8192 + (b) * 4096 + lw]);                                \
    gl16(g_ + (size_t)16 * 512, &pool[8192 + (b) * 4096 + lw + 512]); }

  const int fr = lane & 15;
  const int fg = lane >> 4;
  const int aslot = (fg ^ ((fr >> 1) & 3)) << 3;  // row-mult-16 bases drop out

  f32x4 acc[4][4];
#pragma unroll
  for (int i = 0; i < 4; ++i)
#pragma unroll
    for (int j = 0; j < 4; ++j) acc[i][j] = (f32x4){0.f, 0.f, 0.f, 0.f};
  bf16x8 afr[4], bfr[4];

  // prologue: tile 0 into buf 0
  SA(0, 0) SB(0, 0)
  asm volatile("s_waitcnt vmcnt(0)" ::: "memory");
  __builtin_amdgcn_s_barrier();

#pragma unroll
  for (int kt = 0; kt < 16; ++kt) {
    const int b = kt & 1;
    if (kt < 15) { SA(kt + 1, b ^ 1) SB(kt + 1, b ^ 1) }
#pragma unroll
    for (int mi = 0; mi < 4; ++mi)
      afr[mi] = *reinterpret_cast<const bf16x8*>(
          &pool[b * 4096 + (wm * 64 + mi * 16 + fr) * 32 + aslot]);
#pragma unroll
    for (int ni = 0; ni < 4; ++ni)
      bfr[ni] = *reinterpret_cast<const bf16x8*>(
          &pool[8192 + b * 4096 + (wn * 64 + ni * 16 + fr) * 32 + aslot]);
    asm volatile("s_waitcnt lgkmcnt(0)" ::: "memory");
    __builtin_amdgcn_sched_barrier(0);
    __builtin_amdgcn_s_setprio(1);
#pragma unroll
    for (int mi = 0; mi < 4; ++mi)
#pragma unroll
      for (int ni = 0; ni < 4; ++ni)
        acc[mi][ni] = __builtin_amdgcn_mfma_f32_16x16x32_bf16(
            afr[mi], bfr[ni], acc[mi][ni], 0, 0, 0);
    __builtin_amdgcn_s_setprio(0);
    asm volatile("s_waitcnt vmcnt(0)" ::: "memory");
    __builtin_amdgcn_s_barrier();
  }
#undef SA
#undef SB

  // ---- coalesced epilogue via LDS staging (R4-class, 130-stride) ----
  // acc[mi][ni][r] = C[wm*64+mi*16+fg*4+r][wn*64+ni*16+fr] (m89 layout)
  if constexpr (sizeof(CT) == 2) {
#pragma unroll
    for (int ni = 0; ni < 4; ++ni) {
      int cl = wn * 64 + ni * 16 + fr;
      float bc = bias[n0 + cl];
#pragma unroll
      for (int mi = 0; mi < 4; ++mi) {
        int rl = wm * 64 + mi * 16 + fg * 4;
#pragma unroll
        for (int r = 0; r < 4; ++r)
          pool[(rl + r) * 130 + cl] = f2bf(acc[mi][ni][r] + bc);
      }
    }
    __syncthreads();
#pragma unroll
    for (int it = 0; it < 8; ++it) {
      int idx = it * 256 + t;
      int row = idx >> 4, c8 = idx & 15;
      u16x8 v = *reinterpret_cast<const u16x8*>(&pool[row * 130 + c8 * 8]);
      *reinterpret_cast<u16x8*>(&C[(size_t)(m0 + row) * ldc + n0 + c8 * 8]) = v;
    }
  } else {
    float* stf = reinterpret_cast<float*>(pool);
#pragma unroll
    for (int h = 0; h < 2; ++h) {
      if (wm == h) {
#pragma unroll
        for (int ni = 0; ni < 4; ++ni) {
          int cl = wn * 64 + ni * 16 + fr;
          float bc = bias[n0 + cl];
#pragma unroll
          for (int mi = 0; mi < 4; ++mi) {
            int rl = mi * 16 + fg * 4;
#pragma unroll
            for (int r = 0; r < 4; ++r)
              stf[(rl + r) * 130 + cl] = acc[mi][ni][r] + bc;
          }
        }
      }
      __syncthreads();
#pragma unroll
      for (int it = 0; it < 8; ++it) {
        int idx = it * 256 + t;
        int row = idx >> 5, c4 = idx & 31;
        f32x4 v = *reinterpret_cast<const f32x4*>(&stf[row * 130 + c4 * 4]);
        *reinterpret_cast<f32x4*>(
            &C[(size_t)(m0 + h * 64 + row) * ldc + n0 + c4 * 4]) = v;
      }
      __syncthreads();
    }
  }
}

// ---------------- MFMA attention, double-buffered head pipeline -----------
// (R11-verified.) Block = 256 thr owns 128 rows; wave does 2 windows.
// LDS: K 2x8192 | V 2x8192 | ps 1024 = 33792 shorts.
__global__ __launch_bounds__(256) void attn2(unsigned short* __restrict__ QKV) {
  __shared__ alignas(16) unsigned short sh[33792];
  const int VS = 16384, PS = 32768;
  const int t = threadIdx.x;
  const int lane = t & 63;
  const int w = t >> 6;
  const int fr = lane & 15, fg = lane >> 4, fx = lane & 7;
  const int sr = lane >> 3;
  const int sgx = ((lane & 7) ^ sr) << 3;
  const int sgl = (lane & 7) << 3;
  const size_t m0r = (size_t)blockIdx.x * 128;

#define SK2(h, b)                                                            \
  _Pragma("unroll") for (int u = 0; u < 4; ++u) {                            \
    const int r0 = u * 32 + w * 8;                                           \
    gl16(QKV + (m0r + r0 + sr) * 1536 + 512 + (h) * 64 + sgx,                \
         &sh[(b) * 8192 + r0 * 64]);                                         \
  }
#define SV2(h, b)                                                            \
  _Pragma("unroll") for (int u = 0; u < 4; ++u) {                            \
    const int r0 = u * 32 + w * 8;                                           \
    gl16(QKV + (m0r + r0 + sr) * 1536 + 1024 + (h) * 64 + sgl,               \
         &sh[VS + (b) * 8192 + r0 * 64]);                                    \
  }

  SK2(0, 0) SV2(0, 0)
  asm volatile("s_waitcnt vmcnt(0)" ::: "memory");
  __syncthreads();

  for (int h = 0; h < 8; ++h) {
    const int b = h & 1;
    u16x8 q[2][2];
#pragma unroll
    for (int ww = 0; ww < 2; ++ww) {
      const int wi = w * 2 + ww;
      const unsigned short* qrow = QKV + (m0r + wi * 16 + fr) * 1536 + h * 64;
      q[ww][0] = *reinterpret_cast<const u16x8*>(qrow + fg * 8);
      q[ww][1] = *reinterpret_cast<const u16x8*>(qrow + 32 + fg * 8);
    }
    if (h < 7) { SK2(h + 1, b ^ 1) SV2(h + 1, b ^ 1) }

#pragma unroll
    for (int ww = 0; ww < 2; ++ww) {
      const int wi = w * 2 + ww;
      f32x4 s = (f32x4){0.f, 0.f, 0.f, 0.f};
      {
        bf16x8 kf_ = *reinterpret_cast<const bf16x8*>(
            &sh[b * 8192 + (wi * 16 + fr) * 64 + ((fg ^ fx) << 3)]);
        s = __builtin_amdgcn_mfma_f32_16x16x32_bf16(
            kf_, __builtin_bit_cast(bf16x8, q[ww][0]), s, 0, 0, 0);
        kf_ = *reinterpret_cast<const bf16x8*>(
            &sh[b * 8192 + (wi * 16 + fr) * 64 + (((4 + fg) ^ fx) << 3)]);
        s = __builtin_amdgcn_mfma_f32_16x16x32_bf16(
            kf_, __builtin_bit_cast(bf16x8, q[ww][1]), s, 0, 0, 0);
      }
      u16x4 pfu;
#pragma unroll
      for (int r = 0; r < 4; ++r)
        pfu[r] = f2bf(1.0f / (1.0f + __expf(-s[r] * 0.125f)));
      *reinterpret_cast<u16x4*>(&sh[PS + w * 256 + fr * 16 + fg * 4]) = pfu;
      u16x8 pbu = (u16x8){0, 0, 0, 0, 0, 0, 0, 0};
      if (fg < 2)
        pbu = *reinterpret_cast<const u16x8*>(&sh[PS + w * 256 + fr * 16 + fg * 8]);
      bf16x8 pb = __builtin_bit_cast(bf16x8, pbu);
#pragma unroll
      for (int dc = 0; dc < 4; ++dc) {
        u16x8 vau;
#pragma unroll
        for (int j = 0; j < 8; ++j)
          vau[j] = sh[VS + b * 8192 + (wi * 16 + (fg & 1) * 8 + j) * 64 + dc * 16 + fr];
        f32x4 c = __builtin_amdgcn_mfma_f32_16x16x32_bf16(
            __builtin_bit_cast(bf16x8, vau), pb, (f32x4){0.f, 0.f, 0.f, 0.f},
            0, 0, 0);
        u16x4 o;
#pragma unroll
        for (int r = 0; r < 4; ++r) o[r] = f2bf(c[r]);
        *reinterpret_cast<u16x4*>(
            &QKV[(m0r + wi * 16 + fr) * 1536 + 1024 + h * 64 + dc * 16 + fg * 4]) = o;
      }
    }
    asm volatile("s_waitcnt vmcnt(8)" ::: "memory");
    __syncthreads();
  }
#undef SK2
#undef SV2
}

// --------------------------------------------------------------------------
extern "C" void kernel_launch(void* const* d_in, const int* in_sizes, int n_in,
                              void* d_out, int out_size, void* d_ws, size_t ws_size,
                              hipStream_t stream) {
  const float* x  = (const float*)d_in[0];
  const float* Wq = (const float*)d_in[1];
  const float* bq = (const float*)d_in[2];
  const float* Wk = (const float*)d_in[3];
  const float* bk = (const float*)d_in[4];
  const float* Wv = (const float*)d_in[5];
  const float* bv = (const float*)d_in[6];
  const float* Wo = (const float*)d_in[7];
  const float* bo = (const float*)d_in[8];
  float* out = (float*)d_out;

  const int M = 65536;
  char* ws = (char*)d_ws;
  unsigned short* WT = (unsigned short*)ws;                  // [2048][512] bf16
  float* biasc = (float*)(ws + (size_t)2048 * 512 * 2);      // [1536]
  const long long prep_bytes = (long long)2048 * 512 * 2 + 8192;

  prep_wt<<<dim3(8, 8, 4), 256, 0, stream>>>(Wq, Wk, Wv, Wo, WT);
  prep_bias<<<6, 256, 0, stream>>>(bq, bk, bv, biasc);

  // per-chunk: Xb rows*512*2 + QKV rows*1536*2 = rows*4096 B
  long long avail = (long long)ws_size - prep_bytes;
  int chunk_rows = 65536;
  while (chunk_rows > 2048 && (long long)chunk_rows * 4096 > avail) chunk_rows >>= 1;
  const int nchunks = M / chunk_rows;

  unsigned short* Xb  = (unsigned short*)(ws + prep_bytes);
  unsigned short* QKV = Xb + (size_t)chunk_rows * 512;

  for (int c = 0; c < nchunks; ++c) {
    const size_t row0 = (size_t)c * chunk_rows;
    const int mt = chunk_rows / 128;
    convert_x<<<2048, 256, 0, stream>>>(x + row0 * 512, Xb,
                                        (long long)chunk_rows * 64);
    gemm128<unsigned short><<<mt * 12, 256, 0, stream>>>(
        Xb, 512, WT, QKV, 1536, biasc, 12);
    attn2<<<chunk_rows / 128, 256, 0, stream>>>(QKV);
    gemm128<float><<<mt * 4, 256, 0, stream>>>(
        QKV + 1024, 1536, WT + (size_t)1536 * 512, out + row0 * 512, 512, bo, 4);
  }
}